// Round 8
// baseline (1014.016 us; speedup 1.0000x reference)
//
#include <hip/hip_runtime.h>
#include <stdint.h>

#define NB   4
#define NPTS 2048
#define NROWS (NB * NPTS)   // 8192
#define KNN  64
typedef unsigned long long u64;

// Sinkhorn in base-2 scaled domain: pot2 = pot * log2(e).
#define NEG_SCALE_L2E (-288.53900817779268f)  // -(1/eps)*log2(e)
#define TWO_SCALE_L2E (577.07801635558536f)
#define DEFER_T 24.0f

#define SWZ(i) ((i) + ((i) >> 5))   // LDS float4 swizzle: bank-spread groups
#define COLV_N (NPTS + NPTS / 32)   // 2112

// ---------- helpers ----------

__device__ __forceinline__ float wave_sum(float v) {
#pragma unroll
  for (int o = 32; o >= 1; o >>= 1) v += __shfl_xor(v, o);
  return v;
}
__device__ __forceinline__ float fexp2(float x) {
  float r; asm("v_exp_f32 %0, %1" : "=v"(r) : "v"(x)); return r;
}
__device__ __forceinline__ float flog2(float x) {
  float r; asm("v_log_f32 %0, %1" : "=v"(r) : "v"(x)); return r;
}
__device__ __forceinline__ float sqdist(const float4 a, const float4 c) {
  float dot = a.x * c.x + a.y * c.y + a.z * c.z;
  float d   = a.w + c.w - 2.0f * dot;
  return fmaxf(d, 0.0f);
}
__device__ __forceinline__ uint32_t rotl32(uint32_t x, uint32_t d) {
  return (x << d) | (x >> (32u - d));
}
__device__ __forceinline__ int mbcnt64(u64 m) {
  return __builtin_amdgcn_mbcnt_hi((uint32_t)(m >> 32),
         __builtin_amdgcn_mbcnt_lo((uint32_t)m, 0));
}
__device__ __forceinline__ float2 lse_merge(float2 A, float2 B) {
  float nm = fmaxf(A.x, B.x);
  float s  = fmaf(A.y, fexp2(A.x - nm), B.y * fexp2(B.x - nm));
  return make_float2(nm, s);
}
// All cross-block data moves through agent-scope atomics (bypass per-XCD L2
// both ways), so the barrier needs NO acquire/release cache maintenance.
__device__ __forceinline__ float agent_ld(const float* p) {
  return __hip_atomic_load(p, __ATOMIC_RELAXED, __HIP_MEMORY_SCOPE_AGENT);
}
__device__ __forceinline__ void agent_st(float* p, float v) {
  __hip_atomic_store(p, v, __ATOMIC_RELAXED, __HIP_MEMORY_SCOPE_AGENT);
}

// Per-batch fully-RELAXED hierarchical barrier. 64 blocks = 8 groups x 8.
// Monotonic counters; group counters on separate 128-B lines.
__device__ __forceinline__ void gbar_b(uint32_t* bb, int gi, uint32_t phase) {
  __syncthreads();                     // drains vmcnt: pot stores complete
  if (threadIdx.x == 0) {
    uint32_t* grp  = bb + gi * 32;
    uint32_t* root = bb + 256;
    uint32_t* rel  = bb + 288;
    uint32_t old = __hip_atomic_fetch_add(grp, 1u, __ATOMIC_RELAXED,
                                          __HIP_MEMORY_SCOPE_AGENT);
    if (old == 8u * phase - 1u) {
      uint32_t r = __hip_atomic_fetch_add(root, 1u, __ATOMIC_RELAXED,
                                          __HIP_MEMORY_SCOPE_AGENT);
      if (r == 8u * phase - 1u)
        __hip_atomic_store(rel, phase, __ATOMIC_RELAXED,
                           __HIP_MEMORY_SCOPE_AGENT);
    }
    while (__hip_atomic_load(rel, __ATOMIC_RELAXED,
                             __HIP_MEMORY_SCOPE_AGENT) < phase)
      __builtin_amdgcn_s_sleep(1);
  }
  asm volatile("" ::: "memory");
  __syncthreads();
}

// ---------- kernels ----------

__global__ __launch_bounds__(256) void init_kernel(
    const float* __restrict__ preds, const float* __restrict__ inputs,
    float4* __restrict__ in4, float4* __restrict__ pr4,
    float* __restrict__ lu, float* __restrict__ lv) {
  int i = blockIdx.x * 256 + threadIdx.x;
  if (i >= NROWS) return;
  float ax = inputs[3 * i], ay = inputs[3 * i + 1], az = inputs[3 * i + 2];
  in4[i] = make_float4(ax, ay, az, ax * ax + ay * ay + az * az);
  float px = preds[3 * i], py = preds[3 * i + 1], pz = preds[3 * i + 2];
  pr4[i] = make_float4(px, py, pz, px * px + py * py + pz * pz);
  lu[i] = 0.0f;
  lv[i] = 0.0f;
}

// All 100 Sinkhorn half-steps + assignment. 256 blocks x 1024 threads,
// 1 block/CU (120 KB LDS). Points staged in LDS once (static); per phase we
// fold pot into wcol (SWZ-padded -> conflict-free reads). Thread: 4 rows x
// 16 cols (8 thread-rows x 128 col-groups). Single-pass deferred-rescale
// LSE (threshold 24) with row coords pre-scaled by 2K*log2e (3-FMA dot+y).
__global__ __launch_bounds__(1024, 4) void sink_fused(
    const float4* __restrict__ in4, const float4* __restrict__ pr4,
    float* __restrict__ lu, float* __restrict__ lv,
    float4* __restrict__ perm4, uint32_t* __restrict__ barcnt) {
  __shared__ float4 cin[COLV_N];       // 33792 B  (x,y,z, -K2*|c|^2)
  __shared__ float4 cpr[COLV_N];       // 33792 B
  __shared__ float  wcol[COLV_N];      // 8448 B   (per-phase: col.w + pot)
  __shared__ float2 part[128][33];     // 33792 B
  __shared__ float2 q32m[32][33];      // 8448 B
  __shared__ float2 q8m[8][33];        // 2112 B   (total 120384 B)

  int tid   = threadIdx.x;
  int blk   = blockIdx.x & 63;
  int batch = blockIdx.x >> 6;
  int base  = batch << 11;
  int rblk  = blk << 5;                // 32 rows per block (batch-relative)
  int gi    = blk & 7;
  uint32_t* bb = barcnt + (batch << 9);
  int tr = tid & 7;                    // thread-row (x4 rows)
  int g  = tid >> 3;                   // col-group 0..127 (16 cols)
  int i0 = g << 4;
  int cb = i0 + (i0 >> 5);             // SWZ base; contiguous for 16 cols

  for (int i = tid; i < NPTS; i += 1024) {
    float4 c = in4[base + i];
    cin[SWZ(i)] = make_float4(c.x, c.y, c.z, NEG_SCALE_L2E * c.w);
    float4 p = pr4[base + i];
    cpr[SWZ(i)] = make_float4(p.x, p.y, p.z, NEG_SCALE_L2E * p.w);
  }
  __syncthreads();

  int rl = rblk + tr * 4;
  uint32_t phase = 0;
  for (int it = 0; it < 100; ++it) {
    const float*  pin  = (it & 1) ? lu : lv;
    float*        pout = (it & 1) ? lv : lu;
    const float4* crow = (it & 1) ? cpr : cin;
    const float4* ccol = (it & 1) ? cin : cpr;

    for (int i = tid; i < NPTS; i += 1024)
      wcol[SWZ(i)] = ccol[SWZ(i)].w + agent_ld(&pin[base + i]);
    __syncthreads();

    float4 A0 = crow[SWZ(rl)],     A1 = crow[SWZ(rl + 1)];
    float4 A2 = crow[SWZ(rl + 2)], A3 = crow[SWZ(rl + 3)];
    float a0x = A0.x * TWO_SCALE_L2E, a0y = A0.y * TWO_SCALE_L2E, a0z = A0.z * TWO_SCALE_L2E;
    float a1x = A1.x * TWO_SCALE_L2E, a1y = A1.y * TWO_SCALE_L2E, a1z = A1.z * TWO_SCALE_L2E;
    float a2x = A2.x * TWO_SCALE_L2E, a2y = A2.y * TWO_SCALE_L2E, a2z = A2.z * TWO_SCALE_L2E;
    float a3x = A3.x * TWO_SCALE_L2E, a3y = A3.y * TWO_SCALE_L2E, a3z = A3.z * TWO_SCALE_L2E;
    float mx0 = -INFINITY, mx1 = -INFINITY, mx2 = -INFINITY, mx3 = -INFINITY;
    float mt0 = -INFINITY, mt1 = -INFINITY, mt2 = -INFINITY, mt3 = -INFINITY;
    float s0 = 0.f, s1 = 0.f, s2 = 0.f, s3 = 0.f;
#pragma unroll
    for (int c = 0; c < 16; ++c) {
      float4 cv = ccol[cb + c];
      float  wc = wcol[cb + c];
      float y0 = fmaf(a0x, cv.x, fmaf(a0y, cv.y, fmaf(a0z, cv.z, wc)));
      float y1 = fmaf(a1x, cv.x, fmaf(a1y, cv.y, fmaf(a1z, cv.z, wc)));
      float y2 = fmaf(a2x, cv.x, fmaf(a2y, cv.y, fmaf(a2z, cv.z, wc)));
      float y3 = fmaf(a3x, cv.x, fmaf(a3y, cv.y, fmaf(a3z, cv.z, wc)));
      if (y0 > mt0) { s0 *= fexp2(mx0 - y0); mx0 = y0; mt0 = y0 + DEFER_T; }
      s0 += fexp2(y0 - mx0);
      if (y1 > mt1) { s1 *= fexp2(mx1 - y1); mx1 = y1; mt1 = y1 + DEFER_T; }
      s1 += fexp2(y1 - mx1);
      if (y2 > mt2) { s2 *= fexp2(mx2 - y2); mx2 = y2; mt2 = y2 + DEFER_T; }
      s2 += fexp2(y2 - mx2);
      if (y3 > mt3) { s3 *= fexp2(mx3 - y3); mx3 = y3; mt3 = y3 + DEFER_T; }
      s3 += fexp2(y3 - mx3);
    }
    part[g][tr * 4 + 0] = make_float2(mx0, s0);
    part[g][tr * 4 + 1] = make_float2(mx1, s1);
    part[g][tr * 4 + 2] = make_float2(mx2, s2);
    part[g][tr * 4 + 3] = make_float2(mx3, s3);
    __syncthreads();
    {
      int row = tid & 31, q = tid >> 5;   // 32 quads x 32 rows
      q32m[q][row] = lse_merge(lse_merge(part[4 * q][row], part[4 * q + 1][row]),
                               lse_merge(part[4 * q + 2][row], part[4 * q + 3][row]));
    }
    __syncthreads();
    if (tid < 256) {
      int row = tid & 31, h = tid >> 5;
      q8m[h][row] = lse_merge(lse_merge(q32m[4 * h][row], q32m[4 * h + 1][row]),
                              lse_merge(q32m[4 * h + 2][row], q32m[4 * h + 3][row]));
    }
    __syncthreads();
    if (tid < 32) {
      float2 P = q8m[0][tid];
#pragma unroll
      for (int k = 1; k < 8; ++k) P = lse_merge(P, q8m[k][tid]);
      float aw = crow[SWZ(rblk + tid)].w;   // already -K2*|a|^2
      agent_st(&pout[base + rblk + tid], -11.0f - (flog2(P.y) + P.x + aw));
    }
    gbar_b(bb, gi, ++phase);
  }

  // ---- assignment: argmax_m(logK2 + lv2[m]) per input row ----
  for (int i = tid; i < NPTS; i += 1024)
    wcol[SWZ(i)] = cpr[SWZ(i)].w + agent_ld(&lv[base + i]);
  __syncthreads();
  u64* upart = (u64*)&part[0][0];      // [128][33]
  u64* uq32  = (u64*)&q32m[0][0];      // [32][33]
  u64* uq8   = (u64*)&q8m[0][0];       // [8][33]
  {
    float4 A0 = cin[SWZ(rl)],     A1 = cin[SWZ(rl + 1)];
    float4 A2 = cin[SWZ(rl + 2)], A3 = cin[SWZ(rl + 3)];
    float a0x = A0.x * TWO_SCALE_L2E, a0y = A0.y * TWO_SCALE_L2E, a0z = A0.z * TWO_SCALE_L2E;
    float a1x = A1.x * TWO_SCALE_L2E, a1y = A1.y * TWO_SCALE_L2E, a1z = A1.z * TWO_SCALE_L2E;
    float a2x = A2.x * TWO_SCALE_L2E, a2y = A2.y * TWO_SCALE_L2E, a2z = A2.z * TWO_SCALE_L2E;
    float a3x = A3.x * TWO_SCALE_L2E, a3y = A3.y * TWO_SCALE_L2E, a3z = A3.z * TWO_SCALE_L2E;
    u64 b0 = 0, b1 = 0, b2 = 0, b3 = 0;
#pragma unroll
    for (int c = 0; c < 16; ++c) {
      float4 cv = cpr[cb + c];
      float  wc = wcol[cb + c];
      uint32_t mtag = (uint32_t)(2047 - (i0 + c));
      float y0 = fmaf(a0x, cv.x, fmaf(a0y, cv.y, fmaf(a0z, cv.z, wc)));
      float y1 = fmaf(a1x, cv.x, fmaf(a1y, cv.y, fmaf(a1z, cv.z, wc)));
      float y2 = fmaf(a2x, cv.x, fmaf(a2y, cv.y, fmaf(a2z, cv.z, wc)));
      float y3 = fmaf(a3x, cv.x, fmaf(a3y, cv.y, fmaf(a3z, cv.z, wc)));
      uint32_t u0 = __float_as_uint(y0); u0 = (u0 & 0x80000000u) ? ~u0 : (u0 | 0x80000000u);
      uint32_t u1 = __float_as_uint(y1); u1 = (u1 & 0x80000000u) ? ~u1 : (u1 | 0x80000000u);
      uint32_t u2 = __float_as_uint(y2); u2 = (u2 & 0x80000000u) ? ~u2 : (u2 | 0x80000000u);
      uint32_t u3 = __float_as_uint(y3); u3 = (u3 & 0x80000000u) ? ~u3 : (u3 | 0x80000000u);
      u64 p0 = ((u64)u0 << 32) | mtag; b0 = p0 > b0 ? p0 : b0;
      u64 p1 = ((u64)u1 << 32) | mtag; b1 = p1 > b1 ? p1 : b1;
      u64 p2 = ((u64)u2 << 32) | mtag; b2 = p2 > b2 ? p2 : b2;
      u64 p3 = ((u64)u3 << 32) | mtag; b3 = p3 > b3 ? p3 : b3;
    }
    upart[g * 33 + tr * 4 + 0] = b0;
    upart[g * 33 + tr * 4 + 1] = b1;
    upart[g * 33 + tr * 4 + 2] = b2;
    upart[g * 33 + tr * 4 + 3] = b3;
  }
  __syncthreads();
  {
    int row = tid & 31, q = tid >> 5;
    u64 A = upart[(4 * q) * 33 + row],     B = upart[(4 * q + 1) * 33 + row];
    u64 C = upart[(4 * q + 2) * 33 + row], D = upart[(4 * q + 3) * 33 + row];
    u64 M = A > B ? A : B; u64 N = C > D ? C : D;
    uq32[q * 33 + row] = M > N ? M : N;
  }
  __syncthreads();
  if (tid < 256) {
    int row = tid & 31, h = tid >> 5;
    u64 A = uq32[(4 * h) * 33 + row],     B = uq32[(4 * h + 1) * 33 + row];
    u64 C = uq32[(4 * h + 2) * 33 + row], D = uq32[(4 * h + 3) * 33 + row];
    u64 M = A > B ? A : B; u64 N = C > D ? C : D;
    uq8[h * 33 + row] = M > N ? M : N;
  }
  __syncthreads();
  if (tid < 32) {
    u64 X = uq8[tid];
#pragma unroll
    for (int k = 1; k < 8; ++k) { u64 Y = uq8[k * 33 + tid]; X = Y > X ? Y : X; }
    int m = 2047 - (int)(X & 0xFFFFFFFFu);
    perm4[base + rblk + tid] = pr4[base + m];
  }
}

// Per row (one wave, 4 waves/block): top-65 via 256-bucket histogram on
// sqrt(d) with exact binary-search fallback; no global atomics.
__global__ __launch_bounds__(256) void knn_loss_kernel(
    const float4* __restrict__ in4, const float4* __restrict__ perm4,
    float* __restrict__ partials) {
  __shared__ uint32_t hist[4][256];
  __shared__ u64 cand[4][96];
  __shared__ u64 sel[4][64];
  int tid  = threadIdx.x;
  int wid  = tid >> 6, lane = tid & 63;
  int row  = blockIdx.x * 4 + wid;
  int base = row & ~(NPTS - 1);
  const float4* ip = in4 + base;
  float4 a = in4[row];

  float dv[32];
#pragma unroll
  for (int t = 0; t < 32; ++t) dv[t] = sqdist(a, ip[(t << 6) | lane]);

#pragma unroll
  for (int j = 0; j < 4; ++j) hist[wid][lane * 4 + j] = 0u;
  asm volatile("s_waitcnt lgkmcnt(0)" ::: "memory");
#pragma unroll
  for (int t = 0; t < 32; ++t) {
    int key = (int)fminf(sqrtf(dv[t]) * 32.0f, 255.0f);
    atomicAdd(&hist[wid][key], 1u);
  }
  asm volatile("s_waitcnt lgkmcnt(0)" ::: "memory");

  uint32_t h0 = hist[wid][lane * 4 + 0], h1 = hist[wid][lane * 4 + 1];
  uint32_t h2 = hist[wid][lane * 4 + 2], h3 = hist[wid][lane * 4 + 3];
  uint32_t s4 = h0 + h1 + h2 + h3;
  uint32_t cum = s4;
#pragma unroll
  for (int o = 1; o < 64; o <<= 1) {
    uint32_t n = __shfl_up(cum, o);
    if (lane >= o) cum += n;
  }
  u64 bal = __ballot(cum >= 65u);
  int Bstar = 255;
  uint32_t cnt_sel = 0;
  if (bal != 0) {
    int lstar = __ffsll(bal) - 1;
    uint32_t cpx = __shfl(cum - s4, lstar);
    uint32_t g0 = __shfl(h0, lstar), g1 = __shfl(h1, lstar);
    uint32_t g2 = __shfl(h2, lstar), g3 = __shfl(h3, lstar);
    if      (cpx + g0 >= 65u)           { Bstar = 4 * lstar;     cnt_sel = cpx + g0; }
    else if (cpx + g0 + g1 >= 65u)      { Bstar = 4 * lstar + 1; cnt_sel = cpx + g0 + g1; }
    else if (cpx + g0 + g1 + g2 >= 65u) { Bstar = 4 * lstar + 2; cnt_sel = cpx + g0 + g1 + g2; }
    else                                { Bstar = 4 * lstar + 3; cnt_sel = cpx + g0 + g1 + g2 + g3; }
  }
  bool exact = (bal == 0) || (cnt_sel > 96u);   // wave-uniform, rare

  uint32_t T = 0u;
  if (exact) {
    uint32_t lo = 0u, hi = 0x7F7FFFFFu;
    while (lo < hi) {
      uint32_t mid = lo + ((hi - lo) >> 1);
      int c = 0;
#pragma unroll
      for (int t = 0; t < 32; ++t) c += __popcll(__ballot(__float_as_uint(dv[t]) <= mid));
      if (c >= 65) hi = mid; else lo = mid + 1;
    }
    T = lo;
  }

  int pos = 0;
#pragma unroll
  for (int t = 0; t < 32; ++t) {
    bool pr;
    if (exact) {
      pr = (__float_as_uint(dv[t]) <= T);
    } else {
      int key = (int)fminf(sqrtf(dv[t]) * 32.0f, 255.0f);
      pr = (key <= Bstar);
    }
    u64 m = __ballot(pr);
    if (pr) {
      int idx = pos + mbcnt64(m);
      if (idx < 96)
        cand[wid][idx] = ((u64)__float_as_uint(dv[t]) << 32) | (uint32_t)((t << 6) | lane);
    }
    pos += __popcll(m);
  }
  int nc = pos < 96 ? pos : 96;

  u64 mine0 = (lane < nc) ? cand[wid][lane] : ~0ull;
  u64 mine1 = (lane + 64 < nc) ? cand[wid][lane + 64] : ~0ull;
  int r0 = 0, r1 = 0;
  for (int j = 0; j < nc; ++j) {
    u64 cj = cand[wid][j];
    r0 += (cj < mine0) ? 1 : 0;
    r1 += (cj < mine1) ? 1 : 0;
  }
  if (lane < nc && r0 >= 1 && r0 <= 64) sel[wid][r0 - 1] = mine0;
  if (lane + 64 < nc && r1 >= 1 && r1 <= 64) sel[wid][r1 - 1] = mine1;
  u64 s = sel[wid][lane];
  float kd = __uint_as_float((uint32_t)(s >> 32));
  int   ki = (int)(s & 0xFFFFFFFFu);

  const float C1 = (float)(0.05 * 0.05);
  const float C2 = (float)(2.0 * (0.5657 * 0.5657));
  const float C3 = (float)(0.5657 * 2.5066282746);
  float t2 = (kd / C1) / C2;
  float pr = expf(-t2) / C3;

  // jax.random.uniform(key(42), (4,2048,64)) : threefry2x32, bit-exact
  uint32_t gid = ((uint32_t)row << 6) | (uint32_t)lane;
  const uint32_t HALF = 262144u;
  bool lo2 = gid < HALF;
  uint32_t c0 = lo2 ? gid : (gid - HALF);
  uint32_t c1 = lo2 ? (gid + HALF) : gid;
  const uint32_t k0 = 0u, k1 = 42u;
  const uint32_t k2 = 0x1BD11BDAu ^ k0 ^ k1;
  uint32_t x0 = c0 + k0, x1 = c1 + k1;
#define TF_RND(rr) { x0 += x1; x1 = rotl32(x1, rr); x1 ^= x0; }
  TF_RND(13) TF_RND(15) TF_RND(26) TF_RND(6)
  x0 += k1; x1 += k2 + 1u;
  TF_RND(17) TF_RND(29) TF_RND(16) TF_RND(24)
  x0 += k2; x1 += k0 + 2u;
  TF_RND(13) TF_RND(15) TF_RND(26) TF_RND(6)
  x0 += k0; x1 += k1 + 3u;
  TF_RND(17) TF_RND(29) TF_RND(16) TF_RND(24)
  x0 += k1; x1 += k2 + 4u;
  TF_RND(13) TF_RND(15) TF_RND(26) TF_RND(6)
  x0 += k2; x1 += k0 + 5u;
#undef TF_RND
  uint32_t bits = lo2 ? x0 : x1;
  float u = __uint_as_float((bits >> 9) | 0x3F800000u) - 1.0f;

  bool msk = (u < pr);
  u64 bmask = __ballot(msk);
  int cnt = __popcll(bmask);
  if (cnt == 0 && lane == KNN - 1) msk = true;  // farthest fallback
  float num = (cnt == 0) ? 1.0f : (float)cnt;

  float4 nb = ip[ki];
  float4 pp = perm4[row];
  float dx = pp.x - nb.x, dy = pp.y - nb.y, dz = pp.z - nb.z;
  float dist = dx * dx + dy * dy + dz * dz;
  float contrib = msk ? dist : 0.0f;
  contrib = wave_sum(contrib);
  if (lane == 0) partials[row] = contrib / num;
}

// Sum 8192 per-row partials -> out[0]. One block.
__global__ __launch_bounds__(256) void reduce_kernel(
    const float* __restrict__ partials, float* __restrict__ out) {
  __shared__ float sm[4];
  int tid = threadIdx.x;
  float s = 0.0f;
  for (int i = tid; i < NROWS; i += 256) s += partials[i];
  s = wave_sum(s);
  if ((tid & 63) == 0) sm[tid >> 6] = s;
  __syncthreads();
  if (tid == 0) out[0] = (sm[0] + sm[1]) + (sm[2] + sm[3]);
}

// ---------- launch ----------

extern "C" void kernel_launch(void* const* d_in, const int* in_sizes, int n_in,
                              void* d_out, int out_size, void* d_ws, size_t ws_size,
                              hipStream_t stream) {
  const float* preds  = (const float*)d_in[0];
  const float* inputs = (const float*)d_in[1];
  float* out = (float*)d_out;

  char* ws = (char*)d_ws;
  float4* in4   = (float4*)(ws);             // 131072 B
  float4* pr4   = (float4*)(ws + 131072);    // 131072 B
  float*  lu    = (float*)(ws + 262144);     // 32768 B (base-2 scaled)
  float*  lv    = (float*)(ws + 294912);     // 32768 B (base-2 scaled)
  float4* perm4 = (float4*)(ws + 327680);    // 131072 B
  uint32_t* barcnt = (uint32_t*)(ws + 458752); // 8192 B (4 batches x 2 KB)
  float* partials  = (float*)(ws + 466944);    // 32768 B

  hipMemsetAsync(barcnt, 0, 8192, stream);

  init_kernel<<<NROWS / 256, 256, 0, stream>>>(preds, inputs, in4, pr4, lu, lv);
  sink_fused<<<256, 1024, 0, stream>>>(in4, pr4, lu, lv, perm4, barcnt);
  knn_loss_kernel<<<NROWS / 4, 256, 0, stream>>>(in4, perm4, partials);
  reduce_kernel<<<1, 256, 0, stream>>>(partials, out);
}

// Round 9
// 726.362 us; speedup vs baseline: 1.3960x; 1.3960x over previous
//
#include <hip/hip_runtime.h>
#include <stdint.h>

#define NB   4
#define NPTS 2048
#define NROWS (NB * NPTS)   // 8192
#define KNN  64
typedef unsigned long long u64;

// Sinkhorn in base-2 scaled domain: pot2 = pot * log2(e).
#define NEG_SCALE_L2E (-288.53900817779268f)  // -(1/eps)*log2(e)
#define TWO_SCALE_L2E (577.07801635558536f)

// Group-padded LDS layout: 16-element groups, stride 17 (float4 or float).
// Wave reads 8 consecutive groups (g=tid>>3): float4 word addr = 68g+4c
// -> banks 4g..4g+3 per lane-group = all 32 banks exactly once. Conflict-free.
#define GP(i) (((i) >> 4) * 17 + ((i) & 15))
#define COLV_GP (128 * 17)          // 2176

// ---------- helpers ----------

__device__ __forceinline__ float wave_sum(float v) {
#pragma unroll
  for (int o = 32; o >= 1; o >>= 1) v += __shfl_xor(v, o);
  return v;
}
__device__ __forceinline__ float fexp2(float x) {
  float r; asm("v_exp_f32 %0, %1" : "=v"(r) : "v"(x)); return r;
}
__device__ __forceinline__ float flog2(float x) {
  float r; asm("v_log_f32 %0, %1" : "=v"(r) : "v"(x)); return r;
}
__device__ __forceinline__ float sqdist(const float4 a, const float4 c) {
  float dot = a.x * c.x + a.y * c.y + a.z * c.z;
  float d   = a.w + c.w - 2.0f * dot;
  return fmaxf(d, 0.0f);
}
__device__ __forceinline__ uint32_t rotl32(uint32_t x, uint32_t d) {
  return (x << d) | (x >> (32u - d));
}
__device__ __forceinline__ int mbcnt64(u64 m) {
  return __builtin_amdgcn_mbcnt_hi((uint32_t)(m >> 32),
         __builtin_amdgcn_mbcnt_lo((uint32_t)m, 0));
}
__device__ __forceinline__ float2 lse_merge(float2 A, float2 B) {
  float nm = fmaxf(A.x, B.x);
  float s  = fmaf(A.y, fexp2(A.x - nm), B.y * fexp2(B.x - nm));
  return make_float2(nm, s);
}
// All cross-block data moves through agent-scope atomics (bypass per-XCD L2
// both ways), so the barrier needs NO acquire/release cache maintenance.
__device__ __forceinline__ float agent_ld(const float* p) {
  return __hip_atomic_load(p, __ATOMIC_RELAXED, __HIP_MEMORY_SCOPE_AGENT);
}
__device__ __forceinline__ void agent_st(float* p, float v) {
  __hip_atomic_store(p, v, __ATOMIC_RELAXED, __HIP_MEMORY_SCOPE_AGENT);
}

// Per-batch fully-RELAXED hierarchical barrier. 64 blocks = 8 groups x 8.
__device__ __forceinline__ void gbar_b(uint32_t* bb, int gi, uint32_t phase) {
  __syncthreads();                     // drains vmcnt: pot stores complete
  if (threadIdx.x == 0) {
    uint32_t* grp  = bb + gi * 32;
    uint32_t* root = bb + 256;
    uint32_t* rel  = bb + 288;
    uint32_t old = __hip_atomic_fetch_add(grp, 1u, __ATOMIC_RELAXED,
                                          __HIP_MEMORY_SCOPE_AGENT);
    if (old == 8u * phase - 1u) {
      uint32_t r = __hip_atomic_fetch_add(root, 1u, __ATOMIC_RELAXED,
                                          __HIP_MEMORY_SCOPE_AGENT);
      if (r == 8u * phase - 1u)
        __hip_atomic_store(rel, phase, __ATOMIC_RELAXED,
                           __HIP_MEMORY_SCOPE_AGENT);
    }
    while (__hip_atomic_load(rel, __ATOMIC_RELAXED,
                             __HIP_MEMORY_SCOPE_AGENT) < phase)
      __builtin_amdgcn_s_sleep(1);
  }
  asm volatile("" ::: "memory");
  __syncthreads();
}

// ---------- kernels ----------

__global__ __launch_bounds__(256) void init_kernel(
    const float* __restrict__ preds, const float* __restrict__ inputs,
    float4* __restrict__ in4, float4* __restrict__ pr4,
    float* __restrict__ lu, float* __restrict__ lv) {
  int i = blockIdx.x * 256 + threadIdx.x;
  if (i >= NROWS) return;
  float ax = inputs[3 * i], ay = inputs[3 * i + 1], az = inputs[3 * i + 2];
  in4[i] = make_float4(ax, ay, az, ax * ax + ay * ay + az * az);
  float px = preds[3 * i], py = preds[3 * i + 1], pz = preds[3 * i + 2];
  pr4[i] = make_float4(px, py, pz, px * px + py * py + pz * pz);
  lu[i] = 0.0f;
  lv[i] = 0.0f;
}

// All 100 Sinkhorn half-steps + assignment. 256 blocks x 1024 threads,
// 1 block/CU (~120 KB LDS). Points staged in LDS once (static, group-padded
// conflict-free). Per phase: fold pot into wcol, then TWO-PASS LSE with a
// single exp2 per pair and no branches; wc[] held in regs across passes.
// Thread: 4 rows x 16 cols (8 thread-rows x 128 col-groups).
__global__ __launch_bounds__(1024, 4) void sink_fused(
    const float4* __restrict__ in4, const float4* __restrict__ pr4,
    float* __restrict__ lu, float* __restrict__ lv,
    float4* __restrict__ perm4, uint32_t* __restrict__ barcnt) {
  __shared__ float4 cin[COLV_GP];      // 34816 B  (x,y,z, -K2*|c|^2)
  __shared__ float4 cpr[COLV_GP];      // 34816 B
  __shared__ float  wcol[COLV_GP];     // 8704 B   (per-phase: col.w + pot)
  __shared__ float2 part[128][33];     // 33792 B
  __shared__ float2 q32m[32][33];      // 8448 B
  __shared__ float2 q8m[8][33];        // 2112 B   (total 122688 B)

  int tid   = threadIdx.x;
  int blk   = blockIdx.x & 63;
  int batch = blockIdx.x >> 6;
  int base  = batch << 11;
  int rblk  = blk << 5;                // 32 rows per block (batch-relative)
  int gi    = blk & 7;
  uint32_t* bb = barcnt + (batch << 9);
  int tr = tid & 7;                    // thread-row (x4 rows)
  int g  = tid >> 3;                   // col-group 0..127 (16 cols)
  int i0 = g << 4;
  int cb = g * 17;                     // group-padded base

  for (int i = tid; i < NPTS; i += 1024) {
    float4 c = in4[base + i];
    cin[GP(i)] = make_float4(c.x, c.y, c.z, NEG_SCALE_L2E * c.w);
    float4 p = pr4[base + i];
    cpr[GP(i)] = make_float4(p.x, p.y, p.z, NEG_SCALE_L2E * p.w);
  }
  __syncthreads();

  int rl = rblk + tr * 4;
  uint32_t phase = 0;
  for (int it = 0; it < 100; ++it) {
    const float*  pin  = (it & 1) ? lu : lv;
    float*        pout = (it & 1) ? lv : lu;
    const float4* crow = (it & 1) ? cpr : cin;
    const float4* ccol = (it & 1) ? cin : cpr;

    for (int i = tid; i < NPTS; i += 1024)
      wcol[GP(i)] = ccol[GP(i)].w + agent_ld(&pin[base + i]);
    __syncthreads();

    float4 A0 = crow[GP(rl)],     A1 = crow[GP(rl + 1)];
    float4 A2 = crow[GP(rl + 2)], A3 = crow[GP(rl + 3)];
    float a0x = A0.x * TWO_SCALE_L2E, a0y = A0.y * TWO_SCALE_L2E, a0z = A0.z * TWO_SCALE_L2E;
    float a1x = A1.x * TWO_SCALE_L2E, a1y = A1.y * TWO_SCALE_L2E, a1z = A1.z * TWO_SCALE_L2E;
    float a2x = A2.x * TWO_SCALE_L2E, a2y = A2.y * TWO_SCALE_L2E, a2z = A2.z * TWO_SCALE_L2E;
    float a3x = A3.x * TWO_SCALE_L2E, a3y = A3.y * TWO_SCALE_L2E, a3z = A3.z * TWO_SCALE_L2E;

    float wc[16];
    float mx0 = -INFINITY, mx1 = -INFINITY, mx2 = -INFINITY, mx3 = -INFINITY;
#pragma unroll
    for (int c = 0; c < 16; ++c) {
      float4 cv = ccol[cb + c];
      float  w  = wcol[cb + c];
      wc[c] = w;
      mx0 = fmaxf(mx0, fmaf(a0x, cv.x, fmaf(a0y, cv.y, fmaf(a0z, cv.z, w))));
      mx1 = fmaxf(mx1, fmaf(a1x, cv.x, fmaf(a1y, cv.y, fmaf(a1z, cv.z, w))));
      mx2 = fmaxf(mx2, fmaf(a2x, cv.x, fmaf(a2y, cv.y, fmaf(a2z, cv.z, w))));
      mx3 = fmaxf(mx3, fmaf(a3x, cv.x, fmaf(a3y, cv.y, fmaf(a3z, cv.z, w))));
    }
    float s0 = 0.f, s1 = 0.f, s2 = 0.f, s3 = 0.f;
#pragma unroll
    for (int c = 0; c < 16; ++c) {
      float4 cv = ccol[cb + c];
      float  w  = wc[c];
      s0 += fexp2(fmaf(a0x, cv.x, fmaf(a0y, cv.y, fmaf(a0z, cv.z, w))) - mx0);
      s1 += fexp2(fmaf(a1x, cv.x, fmaf(a1y, cv.y, fmaf(a1z, cv.z, w))) - mx1);
      s2 += fexp2(fmaf(a2x, cv.x, fmaf(a2y, cv.y, fmaf(a2z, cv.z, w))) - mx2);
      s3 += fexp2(fmaf(a3x, cv.x, fmaf(a3y, cv.y, fmaf(a3z, cv.z, w))) - mx3);
    }
    part[g][tr * 4 + 0] = make_float2(mx0, s0);
    part[g][tr * 4 + 1] = make_float2(mx1, s1);
    part[g][tr * 4 + 2] = make_float2(mx2, s2);
    part[g][tr * 4 + 3] = make_float2(mx3, s3);
    __syncthreads();
    {
      int row = tid & 31, q = tid >> 5;   // 32 quads x 32 rows
      q32m[q][row] = lse_merge(lse_merge(part[4 * q][row], part[4 * q + 1][row]),
                               lse_merge(part[4 * q + 2][row], part[4 * q + 3][row]));
    }
    __syncthreads();
    if (tid < 256) {
      int row = tid & 31, h = tid >> 5;
      q8m[h][row] = lse_merge(lse_merge(q32m[4 * h][row], q32m[4 * h + 1][row]),
                              lse_merge(q32m[4 * h + 2][row], q32m[4 * h + 3][row]));
    }
    __syncthreads();
    if (tid < 32) {
      float2 P = q8m[0][tid];
#pragma unroll
      for (int k = 1; k < 8; ++k) P = lse_merge(P, q8m[k][tid]);
      float aw = crow[GP(rblk + tid)].w;   // already -K2*|a|^2
      agent_st(&pout[base + rblk + tid], -11.0f - (flog2(P.y) + P.x + aw));
    }
    gbar_b(bb, gi, ++phase);
  }

  // ---- assignment: argmax_m(logK2 + lv2[m]) per input row ----
  for (int i = tid; i < NPTS; i += 1024)
    wcol[GP(i)] = cpr[GP(i)].w + agent_ld(&lv[base + i]);
  __syncthreads();
  u64* upart = (u64*)&part[0][0];      // [128][33]
  u64* uq32  = (u64*)&q32m[0][0];      // [32][33]
  u64* uq8   = (u64*)&q8m[0][0];       // [8][33]
  {
    float4 A0 = cin[GP(rl)],     A1 = cin[GP(rl + 1)];
    float4 A2 = cin[GP(rl + 2)], A3 = cin[GP(rl + 3)];
    float a0x = A0.x * TWO_SCALE_L2E, a0y = A0.y * TWO_SCALE_L2E, a0z = A0.z * TWO_SCALE_L2E;
    float a1x = A1.x * TWO_SCALE_L2E, a1y = A1.y * TWO_SCALE_L2E, a1z = A1.z * TWO_SCALE_L2E;
    float a2x = A2.x * TWO_SCALE_L2E, a2y = A2.y * TWO_SCALE_L2E, a2z = A2.z * TWO_SCALE_L2E;
    float a3x = A3.x * TWO_SCALE_L2E, a3y = A3.y * TWO_SCALE_L2E, a3z = A3.z * TWO_SCALE_L2E;
    u64 b0 = 0, b1 = 0, b2 = 0, b3 = 0;
#pragma unroll
    for (int c = 0; c < 16; ++c) {
      float4 cv = cpr[cb + c];
      float  w  = wcol[cb + c];
      uint32_t mtag = (uint32_t)(2047 - (i0 + c));
      float y0 = fmaf(a0x, cv.x, fmaf(a0y, cv.y, fmaf(a0z, cv.z, w)));
      float y1 = fmaf(a1x, cv.x, fmaf(a1y, cv.y, fmaf(a1z, cv.z, w)));
      float y2 = fmaf(a2x, cv.x, fmaf(a2y, cv.y, fmaf(a2z, cv.z, w)));
      float y3 = fmaf(a3x, cv.x, fmaf(a3y, cv.y, fmaf(a3z, cv.z, w)));
      uint32_t u0 = __float_as_uint(y0); u0 = (u0 & 0x80000000u) ? ~u0 : (u0 | 0x80000000u);
      uint32_t u1 = __float_as_uint(y1); u1 = (u1 & 0x80000000u) ? ~u1 : (u1 | 0x80000000u);
      uint32_t u2 = __float_as_uint(y2); u2 = (u2 & 0x80000000u) ? ~u2 : (u2 | 0x80000000u);
      uint32_t u3 = __float_as_uint(y3); u3 = (u3 & 0x80000000u) ? ~u3 : (u3 | 0x80000000u);
      u64 p0 = ((u64)u0 << 32) | mtag; b0 = p0 > b0 ? p0 : b0;
      u64 p1 = ((u64)u1 << 32) | mtag; b1 = p1 > b1 ? p1 : b1;
      u64 p2 = ((u64)u2 << 32) | mtag; b2 = p2 > b2 ? p2 : b2;
      u64 p3 = ((u64)u3 << 32) | mtag; b3 = p3 > b3 ? p3 : b3;
    }
    upart[g * 33 + tr * 4 + 0] = b0;
    upart[g * 33 + tr * 4 + 1] = b1;
    upart[g * 33 + tr * 4 + 2] = b2;
    upart[g * 33 + tr * 4 + 3] = b3;
  }
  __syncthreads();
  {
    int row = tid & 31, q = tid >> 5;
    u64 A = upart[(4 * q) * 33 + row],     B = upart[(4 * q + 1) * 33 + row];
    u64 C = upart[(4 * q + 2) * 33 + row], D = upart[(4 * q + 3) * 33 + row];
    u64 M = A > B ? A : B; u64 N = C > D ? C : D;
    uq32[q * 33 + row] = M > N ? M : N;
  }
  __syncthreads();
  if (tid < 256) {
    int row = tid & 31, h = tid >> 5;
    u64 A = uq32[(4 * h) * 33 + row],     B = uq32[(4 * h + 1) * 33 + row];
    u64 C = uq32[(4 * h + 2) * 33 + row], D = uq32[(4 * h + 3) * 33 + row];
    u64 M = A > B ? A : B; u64 N = C > D ? C : D;
    uq8[h * 33 + row] = M > N ? M : N;
  }
  __syncthreads();
  if (tid < 32) {
    u64 X = uq8[tid];
#pragma unroll
    for (int k = 1; k < 8; ++k) { u64 Y = uq8[k * 33 + tid]; X = Y > X ? Y : X; }
    int m = 2047 - (int)(X & 0xFFFFFFFFu);
    perm4[base + rblk + tid] = pr4[base + m];
  }
}

// Per row (one wave, 4 waves/block): top-65 via 256-bucket histogram on
// sqrt(d) with exact binary-search fallback; no global atomics.
__global__ __launch_bounds__(256) void knn_loss_kernel(
    const float4* __restrict__ in4, const float4* __restrict__ perm4,
    float* __restrict__ partials) {
  __shared__ uint32_t hist[4][256];
  __shared__ u64 cand[4][96];
  __shared__ u64 sel[4][64];
  int tid  = threadIdx.x;
  int wid  = tid >> 6, lane = tid & 63;
  int row  = blockIdx.x * 4 + wid;
  int base = row & ~(NPTS - 1);
  const float4* ip = in4 + base;
  float4 a = in4[row];

  float dv[32];
#pragma unroll
  for (int t = 0; t < 32; ++t) dv[t] = sqdist(a, ip[(t << 6) | lane]);

#pragma unroll
  for (int j = 0; j < 4; ++j) hist[wid][lane * 4 + j] = 0u;
  asm volatile("s_waitcnt lgkmcnt(0)" ::: "memory");
#pragma unroll
  for (int t = 0; t < 32; ++t) {
    int key = (int)fminf(sqrtf(dv[t]) * 32.0f, 255.0f);
    atomicAdd(&hist[wid][key], 1u);
  }
  asm volatile("s_waitcnt lgkmcnt(0)" ::: "memory");

  uint32_t h0 = hist[wid][lane * 4 + 0], h1 = hist[wid][lane * 4 + 1];
  uint32_t h2 = hist[wid][lane * 4 + 2], h3 = hist[wid][lane * 4 + 3];
  uint32_t s4 = h0 + h1 + h2 + h3;
  uint32_t cum = s4;
#pragma unroll
  for (int o = 1; o < 64; o <<= 1) {
    uint32_t n = __shfl_up(cum, o);
    if (lane >= o) cum += n;
  }
  u64 bal = __ballot(cum >= 65u);
  int Bstar = 255;
  uint32_t cnt_sel = 0;
  if (bal != 0) {
    int lstar = __ffsll(bal) - 1;
    uint32_t cpx = __shfl(cum - s4, lstar);
    uint32_t g0 = __shfl(h0, lstar), g1 = __shfl(h1, lstar);
    uint32_t g2 = __shfl(h2, lstar), g3 = __shfl(h3, lstar);
    if      (cpx + g0 >= 65u)           { Bstar = 4 * lstar;     cnt_sel = cpx + g0; }
    else if (cpx + g0 + g1 >= 65u)      { Bstar = 4 * lstar + 1; cnt_sel = cpx + g0 + g1; }
    else if (cpx + g0 + g1 + g2 >= 65u) { Bstar = 4 * lstar + 2; cnt_sel = cpx + g0 + g1 + g2; }
    else                                { Bstar = 4 * lstar + 3; cnt_sel = cpx + g0 + g1 + g2 + g3; }
  }
  bool exact = (bal == 0) || (cnt_sel > 96u);   // wave-uniform, rare

  uint32_t T = 0u;
  if (exact) {
    uint32_t lo = 0u, hi = 0x7F7FFFFFu;
    while (lo < hi) {
      uint32_t mid = lo + ((hi - lo) >> 1);
      int c = 0;
#pragma unroll
      for (int t = 0; t < 32; ++t) c += __popcll(__ballot(__float_as_uint(dv[t]) <= mid));
      if (c >= 65) hi = mid; else lo = mid + 1;
    }
    T = lo;
  }

  int pos = 0;
#pragma unroll
  for (int t = 0; t < 32; ++t) {
    bool pr;
    if (exact) {
      pr = (__float_as_uint(dv[t]) <= T);
    } else {
      int key = (int)fminf(sqrtf(dv[t]) * 32.0f, 255.0f);
      pr = (key <= Bstar);
    }
    u64 m = __ballot(pr);
    if (pr) {
      int idx = pos + mbcnt64(m);
      if (idx < 96)
        cand[wid][idx] = ((u64)__float_as_uint(dv[t]) << 32) | (uint32_t)((t << 6) | lane);
    }
    pos += __popcll(m);
  }
  int nc = pos < 96 ? pos : 96;

  u64 mine0 = (lane < nc) ? cand[wid][lane] : ~0ull;
  u64 mine1 = (lane + 64 < nc) ? cand[wid][lane + 64] : ~0ull;
  int r0 = 0, r1 = 0;
  for (int j = 0; j < nc; ++j) {
    u64 cj = cand[wid][j];
    r0 += (cj < mine0) ? 1 : 0;
    r1 += (cj < mine1) ? 1 : 0;
  }
  if (lane < nc && r0 >= 1 && r0 <= 64) sel[wid][r0 - 1] = mine0;
  if (lane + 64 < nc && r1 >= 1 && r1 <= 64) sel[wid][r1 - 1] = mine1;
  u64 s = sel[wid][lane];
  float kd = __uint_as_float((uint32_t)(s >> 32));
  int   ki = (int)(s & 0xFFFFFFFFu);

  const float C1 = (float)(0.05 * 0.05);
  const float C2 = (float)(2.0 * (0.5657 * 0.5657));
  const float C3 = (float)(0.5657 * 2.5066282746);
  float t2 = (kd / C1) / C2;
  float pr = expf(-t2) / C3;

  // jax.random.uniform(key(42), (4,2048,64)) : threefry2x32, bit-exact
  uint32_t gid = ((uint32_t)row << 6) | (uint32_t)lane;
  const uint32_t HALF = 262144u;
  bool lo2 = gid < HALF;
  uint32_t c0 = lo2 ? gid : (gid - HALF);
  uint32_t c1 = lo2 ? (gid + HALF) : gid;
  const uint32_t k0 = 0u, k1 = 42u;
  const uint32_t k2 = 0x1BD11BDAu ^ k0 ^ k1;
  uint32_t x0 = c0 + k0, x1 = c1 + k1;
#define TF_RND(rr) { x0 += x1; x1 = rotl32(x1, rr); x1 ^= x0; }
  TF_RND(13) TF_RND(15) TF_RND(26) TF_RND(6)
  x0 += k1; x1 += k2 + 1u;
  TF_RND(17) TF_RND(29) TF_RND(16) TF_RND(24)
  x0 += k2; x1 += k0 + 2u;
  TF_RND(13) TF_RND(15) TF_RND(26) TF_RND(6)
  x0 += k0; x1 += k1 + 3u;
  TF_RND(17) TF_RND(29) TF_RND(16) TF_RND(24)
  x0 += k1; x1 += k2 + 4u;
  TF_RND(13) TF_RND(15) TF_RND(26) TF_RND(6)
  x0 += k2; x1 += k0 + 5u;
#undef TF_RND
  uint32_t bits = lo2 ? x0 : x1;
  float u = __uint_as_float((bits >> 9) | 0x3F800000u) - 1.0f;

  bool msk = (u < pr);
  u64 bmask = __ballot(msk);
  int cnt = __popcll(bmask);
  if (cnt == 0 && lane == KNN - 1) msk = true;  // farthest fallback
  float num = (cnt == 0) ? 1.0f : (float)cnt;

  float4 nb = ip[ki];
  float4 pp = perm4[row];
  float dx = pp.x - nb.x, dy = pp.y - nb.y, dz = pp.z - nb.z;
  float dist = dx * dx + dy * dy + dz * dz;
  float contrib = msk ? dist : 0.0f;
  contrib = wave_sum(contrib);
  if (lane == 0) partials[row] = contrib / num;
}

// Sum 8192 per-row partials -> out[0]. One block.
__global__ __launch_bounds__(256) void reduce_kernel(
    const float* __restrict__ partials, float* __restrict__ out) {
  __shared__ float sm[4];
  int tid = threadIdx.x;
  float s = 0.0f;
  for (int i = tid; i < NROWS; i += 256) s += partials[i];
  s = wave_sum(s);
  if ((tid & 63) == 0) sm[tid >> 6] = s;
  __syncthreads();
  if (tid == 0) out[0] = (sm[0] + sm[1]) + (sm[2] + sm[3]);
}

// ---------- launch ----------

extern "C" void kernel_launch(void* const* d_in, const int* in_sizes, int n_in,
                              void* d_out, int out_size, void* d_ws, size_t ws_size,
                              hipStream_t stream) {
  const float* preds  = (const float*)d_in[0];
  const float* inputs = (const float*)d_in[1];
  float* out = (float*)d_out;

  char* ws = (char*)d_ws;
  float4* in4   = (float4*)(ws);             // 131072 B
  float4* pr4   = (float4*)(ws + 131072);    // 131072 B
  float*  lu    = (float*)(ws + 262144);     // 32768 B (base-2 scaled)
  float*  lv    = (float*)(ws + 294912);     // 32768 B (base-2 scaled)
  float4* perm4 = (float4*)(ws + 327680);    // 131072 B
  uint32_t* barcnt = (uint32_t*)(ws + 458752); // 8192 B (4 batches x 2 KB)
  float* partials  = (float*)(ws + 466944);    // 32768 B

  hipMemsetAsync(barcnt, 0, 8192, stream);

  init_kernel<<<NROWS / 256, 256, 0, stream>>>(preds, inputs, in4, pr4, lu, lv);
  sink_fused<<<256, 1024, 0, stream>>>(in4, pr4, lu, lv, perm4, barcnt);
  knn_loss_kernel<<<NROWS / 4, 256, 0, stream>>>(in4, perm4, partials);
  reduce_kernel<<<1, 256, 0, stream>>>(partials, out);
}